// Round 9
// baseline (57.509 us; speedup 1.0000x reference)
//
#include <hip/hip_runtime.h>

typedef unsigned short u16;
typedef _Float16 f16x2 __attribute__((ext_vector_type(2)));
typedef _Float16 f16x8 __attribute__((ext_vector_type(8)));
typedef float    f32x4  __attribute__((ext_vector_type(4)));
typedef float    f32x16 __attribute__((ext_vector_type(16)));

// Fragment k-map convention (same in BOTH operand slots — proven r1-r8):
//   k_local(lane, j) = (lane>>5)*4 + (j&3) + 8*(j>>2),  j = 0..7
// D layout (m74/m101): col = lane&31 (N), row = (r&3)+8*(r>>2)+4*(lane>>5) (M)

union U4 { uint4 u; f16x8 h; u16 s[8]; };
union HU { f16x2 h2[4]; f16x8 h8; };

// ---------------------------------------------------------------------------
// Prep (r8-identical): Bf = W2flat (2080 x 32, f16) in MFMA B-fragment order
// [0,133120); W1f fragments [133120,135168); b1p permuted bias f32
// [135168,135424): b1p[h][nt][r] = b1[nt*32 + (r&3)+8*(r>>2)+4h]
// ---------------------------------------------------------------------------
__global__ void prep_kernel(const float* __restrict__ W1,
                            const float* __restrict__ b1,
                            const float* __restrict__ W2,
                            const float* __restrict__ b2,
                            u16* __restrict__ ws)
{
    int id = blockIdx.x * 256 + threadIdx.x;
    if (id < 8320) {                       // 130 ksteps * 64 lanes
        int k2 = id >> 6, l = id & 63;
        int h = l >> 5, col = l & 31;
        U4 o;
        #pragma unroll
        for (int g = 0; g < 2; ++g) {
            int base4 = k2 * 16 + g * 8 + h * 4;   // 4-aligned, no 32-straddle
            f32x4 v;
            if (base4 < 2048) {
                int k1 = base4 >> 5, j32 = base4 & 31;
                v = *(const f32x4*)&W2[k1 * 1024 + col * 32 + j32];
            } else {
                v = *(const f32x4*)&b2[col * 32 + (base4 - 2048)];
            }
            #pragma unroll
            for (int j = 0; j < 4; ++j)
                o.h[g * 4 + j] = (_Float16)v[j];
        }
        *(uint4*)(ws + id * 8) = o.u;
    } else if (id < 8448) {                // W1 fragments: 2 ntiles * 64 lanes
        int idx = id - 8320;
        int nt = idx >> 6, l = idx & 63;
        int h = l >> 5, col = nt * 32 + (l & 31);
        U4 o;
        #pragma unroll
        for (int g = 0; g < 2; ++g)
            #pragma unroll
            for (int j = 0; j < 4; ++j) {
                int k = g * 8 + h * 4 + j;
                o.h[g * 4 + j] = (_Float16)W1[k * 64 + col];
            }
        *(uint4*)(ws + id * 8) = o.u;
    } else if (id < 8512) {                // b1p: 2h * 2nt * 16r floats
        int idx = id - 8448;
        int hh = idx >> 5, nt = (idx >> 4) & 1, r = idx & 15;
        int row = (r & 3) + 8 * (r >> 2) + 4 * hh;
        ((float*)(ws + 67584))[idx] = b1[nt * 32 + row];
    }
}

__device__ __forceinline__ void stage16(const void* g, void* l) {
    __builtin_amdgcn_global_load_lds(
        (const __attribute__((address_space(1))) void*)g,
        (__attribute__((address_space(3))) void*)l, 16, 0, 0);
}

// ---------------------------------------------------------------------------
// Main kernel: per-wave code identical to r8 (64 edges/wave, Q-in-regs via
// transposed layer-1 + shfl, 4 acc chains, 84 VGPR proven). ONLY the block
// geometry changes to fix residency (the r1-r8 invariant: Occupancy ~20% =
// 1.6 waves/SIMD because grid 977 / 256 CUs = 3.8 blocks/CU):
//   128-thread blocks (2 waves), 8 KB chunks double-buffered (16 KB LDS),
//   grid = 1954 blocks = 7.6 blocks/CU; caps: LDS 10/CU, VGPR(128,4) 8/CU
//   -> resident ~7 blocks = 14 waves/CU (~44%), 3.5 waves/SIMD to hide
//   ds_read/L2 latency. K loop: 16 chunks x 4 k1 + bias-row tail.
// ---------------------------------------------------------------------------
__global__ __launch_bounds__(128, 4) void edge_kernel(
    const float* __restrict__ h_w,
    const float* __restrict__ ef,
    const u16*  __restrict__ ws,
    float* __restrict__ out,
    int E)
{
    __shared__ alignas(16) u16 shm[8192];   // 16 KB = 2 x 8 KB chunks
    const int tid  = threadIdx.x;
    const int lane = tid & 63;
    const int l31  = lane & 31;
    const int h    = lane >> 5;
    const int tileBase = (blockIdx.x * 2 + (tid >> 6)) * 64;
    const char* wsb = (const char*)ws;
    char*       shb = (char*)shm;

    // ---- stage chunk 0 (8 KB = k1 0..3) ----
    #pragma unroll
    for (int j = 0; j < 4; ++j)
        stage16(wsb + j * 2048 + tid * 16, shb + j * 2048 + tid * 16);

    // ---- h_w fragments (issued early; f16, kept in regs) ----
    f16x2 hwA[2][2][4];
    #pragma unroll
    for (int mt = 0; mt < 2; ++mt) {
        int e = tileBase + mt * 32 + l31;
        bool ok = e < E;
        f32x4 q0 = {}, q1 = {}, q2 = {}, q3 = {};
        if (ok) {
            const float* hp = h_w + (size_t)e * 32 + h * 4;
            q0 = *(const f32x4*)(hp);
            q1 = *(const f32x4*)(hp + 8);
            q2 = *(const f32x4*)(hp + 16);
            q3 = *(const f32x4*)(hp + 24);
        }
        hwA[mt][0][0] = f16x2{ (_Float16)q0[0], (_Float16)q0[1] };
        hwA[mt][0][1] = f16x2{ (_Float16)q0[2], (_Float16)q0[3] };
        hwA[mt][0][2] = f16x2{ (_Float16)q1[0], (_Float16)q1[1] };
        hwA[mt][0][3] = f16x2{ (_Float16)q1[2], (_Float16)q1[3] };
        hwA[mt][1][0] = f16x2{ (_Float16)q2[0], (_Float16)q2[1] };
        hwA[mt][1][1] = f16x2{ (_Float16)q2[2], (_Float16)q2[3] };
        hwA[mt][1][2] = f16x2{ (_Float16)q3[0], (_Float16)q3[1] };
        hwA[mt][1][3] = f16x2{ (_Float16)q3[2], (_Float16)q3[3] };
    }

    // ---- layer 1 (transposed): c = mfma(W1f as A, ef as B) ----
    const uint4* W1f = (const uint4*)(ws + 8320 * 8);
    U4 w1f0, w1f1;
    w1f0.u = W1f[lane];
    w1f1.u = W1f[64 + lane];
    const float* b1pf = (const float*)(ws + 67584);
    f32x4 bv[2][4];
    #pragma unroll
    for (int nt = 0; nt < 2; ++nt)
        #pragma unroll
        for (int qr = 0; qr < 4; ++qr)
            bv[nt][qr] = *(const f32x4*)(b1pf + h * 32 + nt * 16 + qr * 4);

    f16x2 Q[2][2][8][2];   // [mt][nt][p][hq]  — all indices compile-time
    #pragma unroll
    for (int mt = 0; mt < 2; ++mt) {
        int e = tileBase + mt * 32 + l31;
        bool ok = e < E;
        f32x4 g0 = {}, g1 = {};
        if (ok) {
            g0 = *(const f32x4*)&ef[e * 16 + h * 4];
            g1 = *(const f32x4*)&ef[e * 16 + 8 + h * 4];
        }
        U4 a;
        #pragma unroll
        for (int j = 0; j < 4; ++j) {
            a.h[j]     = (_Float16)g0[j];
            a.h[4 + j] = (_Float16)g1[j];
        }
        f32x16 c0 = {}, c1 = {};
        c0 = __builtin_amdgcn_mfma_f32_32x32x16_f16(w1f0.h, a.h, c0, 0, 0, 0);
        c1 = __builtin_amdgcn_mfma_f32_32x32x16_f16(w1f1.h, a.h, c1, 0, 0, 0);
        #pragma unroll
        for (int nt = 0; nt < 2; ++nt) {
            #pragma unroll
            for (int p = 0; p < 8; ++p) {
                float r0 = (nt ? c1[2 * p]     : c0[2 * p]);
                float r1 = (nt ? c1[2 * p + 1] : c0[2 * p + 1]);
                float v0 = fmaxf(r0 + bv[nt][p >> 1][(2 * p) & 3],     0.f);
                float v1 = fmaxf(r1 + bv[nt][p >> 1][(2 * p + 1) & 3], 0.f);
                f16x2 own = { (_Float16)v0, (_Float16)v1 };
                unsigned swu = __shfl_xor(__builtin_bit_cast(unsigned, own), 32, 64);
                f16x2 sw = __builtin_bit_cast(f16x2, swu);
                Q[mt][nt][p][0] = h ? sw : own;   // hq = 0 version
                Q[mt][nt][p][1] = h ? own : sw;   // hq = 1 version
            }
        }
    }

    // 4 independent accumulator chains: [mt][parity of k1]
    f32x16 accA[2] = {}, accB[2] = {};
    __syncthreads();   // chunk-0 stage drained

    // ---- K loop: 16 chunks x 4 k1, fully unrolled (static Q indexing) ----
    #pragma unroll
    for (int c = 0; c < 16; ++c) {
        if (c < 15) {                      // stage chunk c+1 (8 KB)
            #pragma unroll
            for (int j = 0; j < 4; ++j)
                stage16(wsb + (c + 1) * 8192 + j * 2048 + tid * 16,
                        shb + ((c + 1) & 1) * 8192 + j * 2048 + tid * 16);
        } else {                           // stage tail (2 KB, ksteps 128-129) into buf0
            stage16(wsb + 131072 + tid * 16, shb + tid * 16);
        }
        const char* bB = shb + (c & 1) * 8192;
        #pragma unroll
        for (int qq = 0; qq < 4; ++qq) {
            const int k1   = c * 4 + qq;
            const int nt   = k1 >> 5;
            const int q    = k1 & 31;
            const int pa   = ((q & 3) >> 1) + 2 * (q >> 3);
            const int half = q & 1;
            const int hq   = (q >> 2) & 1;
            U4 bf0, bf1;
            bf0.u = *(const uint4*)(bB + (2 * qq) * 1024 + lane * 16);
            bf1.u = *(const uint4*)(bB + (2 * qq + 1) * 1024 + lane * 16);
            _Float16 x0 = Q[0][nt][pa][hq][half];
            _Float16 x1 = Q[1][nt][pa][hq][half];
            f16x2 hh0 = { x0, x0 }, hh1 = { x1, x1 };
            HU A0, A1;
            #pragma unroll
            for (int rr = 0; rr < 4; ++rr) { A0.h2[rr] = hh0 * hwA[0][0][rr]; A1.h2[rr] = hh1 * hwA[1][0][rr]; }
            if (qq & 1) {
                accB[0] = __builtin_amdgcn_mfma_f32_32x32x16_f16(A0.h8, bf0.h, accB[0], 0, 0, 0);
                accB[1] = __builtin_amdgcn_mfma_f32_32x32x16_f16(A1.h8, bf0.h, accB[1], 0, 0, 0);
            } else {
                accA[0] = __builtin_amdgcn_mfma_f32_32x32x16_f16(A0.h8, bf0.h, accA[0], 0, 0, 0);
                accA[1] = __builtin_amdgcn_mfma_f32_32x32x16_f16(A1.h8, bf0.h, accA[1], 0, 0, 0);
            }
            #pragma unroll
            for (int rr = 0; rr < 4; ++rr) { A0.h2[rr] = hh0 * hwA[0][1][rr]; A1.h2[rr] = hh1 * hwA[1][1][rr]; }
            if (qq & 1) {
                accB[0] = __builtin_amdgcn_mfma_f32_32x32x16_f16(A0.h8, bf1.h, accB[0], 0, 0, 0);
                accB[1] = __builtin_amdgcn_mfma_f32_32x32x16_f16(A1.h8, bf1.h, accB[1], 0, 0, 0);
            } else {
                accA[0] = __builtin_amdgcn_mfma_f32_32x32x16_f16(A0.h8, bf1.h, accA[0], 0, 0, 0);
                accA[1] = __builtin_amdgcn_mfma_f32_32x32x16_f16(A1.h8, bf1.h, accA[1], 0, 0, 0);
            }
        }
        __syncthreads();
    }

    // ---- tail k1 = 64 (hdn == 1): A-frag = hwA directly, B in buf0 ----
    {
        U4 bf0, bf1;
        bf0.u = *(const uint4*)(shb + lane * 16);
        bf1.u = *(const uint4*)(shb + 1024 + lane * 16);
        HU A0, A1;
        #pragma unroll
        for (int rr = 0; rr < 4; ++rr) { A0.h2[rr] = hwA[0][0][rr]; A1.h2[rr] = hwA[1][0][rr]; }
        accA[0] = __builtin_amdgcn_mfma_f32_32x32x16_f16(A0.h8, bf0.h, accA[0], 0, 0, 0);
        accA[1] = __builtin_amdgcn_mfma_f32_32x32x16_f16(A1.h8, bf0.h, accA[1], 0, 0, 0);
        #pragma unroll
        for (int rr = 0; rr < 4; ++rr) { A0.h2[rr] = hwA[0][1][rr]; A1.h2[rr] = hwA[1][1][rr]; }
        accA[0] = __builtin_amdgcn_mfma_f32_32x32x16_f16(A0.h8, bf1.h, accA[0], 0, 0, 0);
        accA[1] = __builtin_amdgcn_mfma_f32_32x32x16_f16(A1.h8, bf1.h, accA[1], 0, 0, 0);
    }

    // ---- store messages (sum the two chains) ----
    #pragma unroll
    for (int mt = 0; mt < 2; ++mt) {
        #pragma unroll
        for (int r = 0; r < 16; ++r) {
            int row = (r & 3) + 8 * (r >> 2) + 4 * h;
            int e = tileBase + mt * 32 + row;
            if (e < E) out[(size_t)e * 32 + l31] = accA[mt][r] + accB[mt][r];
        }
    }
}

extern "C" void kernel_launch(void* const* d_in, const int* in_sizes, int n_in,
                              void* d_out, int out_size, void* d_ws, size_t ws_size,
                              hipStream_t stream)
{
    // inputs: 0=h_v (unused), 1=h_w, 2=edge_features, 3=W1, 4=b1, 5=W2, 6=b2
    const float* h_w = (const float*)d_in[1];
    const float* ef  = (const float*)d_in[2];
    const float* W1  = (const float*)d_in[3];
    const float* b1  = (const float*)d_in[4];
    const float* W2  = (const float*)d_in[5];
    const float* b2  = (const float*)d_in[6];
    float* out = (float*)d_out;
    const int E = in_sizes[1] / 32;
    u16* ws = (u16*)d_ws;   // needs 135,424 B

    prep_kernel<<<34, 256, 0, stream>>>(W1, b1, W2, b2, ws);

    const int blocks = (E + 127) / 128;   // 1954 -> 7.6 blocks/CU
    edge_kernel<<<blocks, 128, 0, stream>>>(h_w, ef, ws, out, E);
}

// Round 11
// 51.912 us; speedup vs baseline: 1.1078x; 1.1078x over previous
//
#include <hip/hip_runtime.h>

typedef unsigned short u16;
typedef _Float16 f16x2 __attribute__((ext_vector_type(2)));
typedef _Float16 f16x8 __attribute__((ext_vector_type(8)));
typedef float    f32x4  __attribute__((ext_vector_type(4)));
typedef float    f32x16 __attribute__((ext_vector_type(16)));

// Fragment k-map convention (same in BOTH operand slots — proven r1-r9):
//   k_local(lane, j) = (lane>>5)*4 + (j&3) + 8*(j>>2),  j = 0..7
// D layout (m74/m101): col = lane&31 (N), row = (r&3)+8*(r>>2)+4*(lane>>5) (M)

union U4 { uint4 u; f16x8 h; u16 s[8]; };
union HU { f16x2 h2[4]; f16x8 h8; };

// ---------------------------------------------------------------------------
// Prep (r6 layout): ws bytes:
//   [0,139264)        Bf = W2flat in B-fragment order, 136 ksteps (68 k1):
//                     0..127 = W2, 128..129 = b2 rows, 130..135 = ZERO pad
//   [139264,141312)   W1f fragments (col = nt*32 + l31)
//   [141312,143360)   (spare, unused)
//   [143360,143616)   b1p[h][nt][r] = b1[nt*32 + (r&3)+8*(r>>2)+4h]  (f32)
// ---------------------------------------------------------------------------
__global__ void prep_kernel(const float* __restrict__ W1,
                            const float* __restrict__ b1,
                            const float* __restrict__ W2,
                            const float* __restrict__ b2,
                            u16* __restrict__ ws)
{
    int id = blockIdx.x * 256 + threadIdx.x;
    if (id < 8704) {                       // 136 ksteps * 64 lanes
        int k2 = id >> 6, l = id & 63;
        int h = l >> 5, col = l & 31;
        U4 o;
        if (k2 < 130) {
            #pragma unroll
            for (int g = 0; g < 2; ++g) {
                int base4 = k2 * 16 + g * 8 + h * 4;   // 4-aligned
                f32x4 v;
                if (base4 < 2048) {
                    int k1 = base4 >> 5, j32 = base4 & 31;
                    v = *(const f32x4*)&W2[k1 * 1024 + col * 32 + j32];
                } else {
                    v = *(const f32x4*)&b2[col * 32 + (base4 - 2048)];
                }
                #pragma unroll
                for (int j = 0; j < 4; ++j)
                    o.h[g * 4 + j] = (_Float16)v[j];
            }
        } else {
            o.u = uint4{0u, 0u, 0u, 0u};   // zero-pad k1 65..67
        }
        *(uint4*)(ws + id * 8) = o.u;
    } else if (id < 8832) {                // W1f: 2 ntiles * 64 lanes
        int idx = id - 8704;
        int nt = (idx >> 6) & 1, l = idx & 63;
        int h = l >> 5, col = nt * 32 + (l & 31);
        U4 o;
        #pragma unroll
        for (int g = 0; g < 2; ++g)
            #pragma unroll
            for (int j = 0; j < 4; ++j) {
                int k = g * 8 + h * 4 + j;
                o.h[g * 4 + j] = (_Float16)W1[k * 64 + col];
            }
        *(uint4*)(ws + 69632 + idx * 8) = o.u;
    } else if (id < 8896) {                // b1p: 2h * 2nt * 16r floats
        int idx = id - 8832;
        int hh = idx >> 5, nt = (idx >> 4) & 1, r = idx & 15;
        int row = (r & 3) + 8 * (r >> 2) + 4 * hh;
        ((float*)(ws + 71680))[idx] = b1[nt * 32 + row];
    }
}

__device__ __forceinline__ void stage16(const void* g, void* l) {
    __builtin_amdgcn_global_load_lds(
        (const __attribute__((address_space(1))) void*)g,
        (__attribute__((address_space(3))) void*)l, 16, 0, 0);
}

// ---------------------------------------------------------------------------
// Main kernel: r8 per-wave code verbatim; ONLY the inter-chunk sync changes:
//   - 3 x 16 KB LDS buffer rotation (48 KB -> still 3 blocks/CU)
//   - stage chunk c+2 at the top of chunk c (2 chunk-times of latency cover)
//   - chunk boundary: s_waitcnt vmcnt(4) + raw s_barrier — loads for c+2
//     STAY IN FLIGHT across the barrier (T4 counted-vmcnt; never drain to 0
//     in the main loop). __syncthreads' implicit vmcnt(0) drain was the
//     structural ~72% stall per m233's 2-phase measurement.
//   - T5 setprio(1) around each 4-MFMA group (waves now role-split).
// 9 chunks: c0..c7 = 8 k1 (16 KB), c8 = 4 k1 (8 KB: bias row + zero pad).
// ---------------------------------------------------------------------------
__global__ __launch_bounds__(256, 3) void edge_kernel(
    const float* __restrict__ h_w,
    const float* __restrict__ ef,
    const u16*  __restrict__ ws,
    float* __restrict__ out,
    int E)
{
    __shared__ alignas(16) u16 shm[24576];   // 48 KB = 3 x 16 KB
    const int tid  = threadIdx.x;
    const int lane = tid & 63;
    const int l31  = lane & 63 & 31;
    const int h    = lane >> 5;
    const int tileBase = (blockIdx.x * 4 + (tid >> 6)) * 64;
    const char* wsb = (const char*)ws;
    char*       shb = (char*)shm;

    // ---- prologue stages: chunk 0 -> buf0, chunk 1 -> buf1 (8 loads/wave) ----
    #pragma unroll
    for (int j = 0; j < 4; ++j)
        stage16(wsb + j * 4096 + tid * 16, shb + j * 4096 + tid * 16);
    #pragma unroll
    for (int j = 0; j < 4; ++j)
        stage16(wsb + 16384 + j * 4096 + tid * 16, shb + 16384 + j * 4096 + tid * 16);

    // ---- h_w fragments (issued early; f16, kept in regs) ----
    f16x2 hwA[2][2][4];
    #pragma unroll
    for (int mt = 0; mt < 2; ++mt) {
        int e = tileBase + mt * 32 + l31;
        bool ok = e < E;
        f32x4 q0 = {}, q1 = {}, q2 = {}, q3 = {};
        if (ok) {
            const float* hp = h_w + (size_t)e * 32 + h * 4;
            q0 = *(const f32x4*)(hp);
            q1 = *(const f32x4*)(hp + 8);
            q2 = *(const f32x4*)(hp + 16);
            q3 = *(const f32x4*)(hp + 24);
        }
        hwA[mt][0][0] = f16x2{ (_Float16)q0[0], (_Float16)q0[1] };
        hwA[mt][0][1] = f16x2{ (_Float16)q0[2], (_Float16)q0[3] };
        hwA[mt][0][2] = f16x2{ (_Float16)q1[0], (_Float16)q1[1] };
        hwA[mt][0][3] = f16x2{ (_Float16)q1[2], (_Float16)q1[3] };
        hwA[mt][1][0] = f16x2{ (_Float16)q2[0], (_Float16)q2[1] };
        hwA[mt][1][1] = f16x2{ (_Float16)q2[2], (_Float16)q2[3] };
        hwA[mt][1][2] = f16x2{ (_Float16)q3[0], (_Float16)q3[1] };
        hwA[mt][1][3] = f16x2{ (_Float16)q3[2], (_Float16)q3[3] };
    }

    // ---- layer 1 (transposed): c = mfma(W1f as A, ef as B) ----
    const uint4* W1f = (const uint4*)(ws + 69632);
    U4 w1f0, w1f1;
    w1f0.u = W1f[lane];
    w1f1.u = W1f[64 + lane];
    const float* b1pf = (const float*)(ws + 71680);
    f32x4 bv[2][4];
    #pragma unroll
    for (int nt = 0; nt < 2; ++nt)
        #pragma unroll
        for (int qr = 0; qr < 4; ++qr)
            bv[nt][qr] = *(const f32x4*)(b1pf + h * 32 + nt * 16 + qr * 4);

    f16x2 Q[2][2][8][2];   // [mt][nt][p][hq]  — all indices compile-time
    #pragma unroll
    for (int mt = 0; mt < 2; ++mt) {
        int e = tileBase + mt * 32 + l31;
        bool ok = e < E;
        f32x4 g0 = {}, g1 = {};
        if (ok) {
            g0 = *(const f32x4*)&ef[e * 16 + h * 4];
            g1 = *(const f32x4*)&ef[e * 16 + 8 + h * 4];
        }
        U4 a;
        #pragma unroll
        for (int j = 0; j < 4; ++j) {
            a.h[j]     = (_Float16)g0[j];
            a.h[4 + j] = (_Float16)g1[j];
        }
        f32x16 c0 = {}, c1 = {};
        c0 = __builtin_amdgcn_mfma_f32_32x32x16_f16(w1f0.h, a.h, c0, 0, 0, 0);
        c1 = __builtin_amdgcn_mfma_f32_32x32x16_f16(w1f1.h, a.h, c1, 0, 0, 0);
        #pragma unroll
        for (int nt = 0; nt < 2; ++nt) {
            #pragma unroll
            for (int p = 0; p < 8; ++p) {
                float r0 = (nt ? c1[2 * p]     : c0[2 * p]);
                float r1 = (nt ? c1[2 * p + 1] : c0[2 * p + 1]);
                float v0 = fmaxf(r0 + bv[nt][p >> 1][(2 * p) & 3],     0.f);
                float v1 = fmaxf(r1 + bv[nt][p >> 1][(2 * p + 1) & 3], 0.f);
                f16x2 own = { (_Float16)v0, (_Float16)v1 };
                unsigned swu = __shfl_xor(__builtin_bit_cast(unsigned, own), 32, 64);
                f16x2 sw = __builtin_bit_cast(f16x2, swu);
                Q[mt][nt][p][0] = h ? sw : own;   // hq = 0 version
                Q[mt][nt][p][1] = h ? own : sw;   // hq = 1 version
            }
        }
    }

    // 4 independent accumulator chains: [mt][parity of k1]
    f32x16 accA[2] = {}, accB[2] = {};

    // counted wait: chunk-0's 4 loads done, chunk-1's may stay in flight
    asm volatile("s_waitcnt vmcnt(4)" ::: "memory");
    __builtin_amdgcn_sched_barrier(0);
    __builtin_amdgcn_s_barrier();

    // ---- K loop: 9 chunks, 3-buffer rotation, counted-vmcnt boundaries ----
    #pragma unroll
    for (int c = 0; c < 9; ++c) {
        // stage chunk c+2 -> buf (c+2)%3  (issued FIRST: 2 chunks of cover)
        if (c + 2 <= 7) {
            #pragma unroll
            for (int j = 0; j < 4; ++j)
                stage16(wsb + (c + 2) * 16384 + j * 4096 + tid * 16,
                        shb + ((c + 2) % 3) * 16384 + j * 4096 + tid * 16);
        } else if (c + 2 == 8) {           // 8 KB tail chunk (k1 64..67)
            #pragma unroll
            for (int j = 0; j < 2; ++j)
                stage16(wsb + 131072 + j * 4096 + tid * 16,
                        shb + (8 % 3) * 16384 + j * 4096 + tid * 16);
        }
        // compute chunk c from buf c%3
        const char* bB = shb + (c % 3) * 16384;
        const int nk = (c < 8) ? 8 : 4;
        #pragma unroll
        for (int qq = 0; qq < 8; ++qq) {
            if (qq >= nk) break;
            const int k1 = c * 8 + qq;
            U4 bf0, bf1;
            bf0.u = *(const uint4*)(bB + (2 * qq) * 1024 + lane * 16);
            bf1.u = *(const uint4*)(bB + (2 * qq + 1) * 1024 + lane * 16);
            HU A0, A1, B0, B1;
            if (k1 < 64) {
                const int nt   = k1 >> 5;
                const int q    = k1 & 31;
                const int pa   = ((q & 3) >> 1) + 2 * (q >> 3);
                const int half = q & 1;
                const int hq   = (q >> 2) & 1;
                _Float16 x0 = Q[0][nt][pa][hq][half];
                _Float16 x1 = Q[1][nt][pa][hq][half];
                f16x2 hh0 = { x0, x0 }, hh1 = { x1, x1 };
                #pragma unroll
                for (int rr = 0; rr < 4; ++rr) {
                    A0.h2[rr] = hh0 * hwA[0][0][rr];
                    A1.h2[rr] = hh1 * hwA[1][0][rr];
                    B0.h2[rr] = hh0 * hwA[0][1][rr];
                    B1.h2[rr] = hh1 * hwA[1][1][rr];
                }
            } else {                       // bias row (hdn==1) / zero-pad rows
                #pragma unroll
                for (int rr = 0; rr < 4; ++rr) {
                    A0.h2[rr] = hwA[0][0][rr];
                    A1.h2[rr] = hwA[1][0][rr];
                    B0.h2[rr] = hwA[0][1][rr];
                    B1.h2[rr] = hwA[1][1][rr];
                }
            }
            __builtin_amdgcn_s_setprio(1);
            if (k1 & 1) {
                accB[0] = __builtin_amdgcn_mfma_f32_32x32x16_f16(A0.h8, bf0.h, accB[0], 0, 0, 0);
                accB[1] = __builtin_amdgcn_mfma_f32_32x32x16_f16(A1.h8, bf0.h, accB[1], 0, 0, 0);
                accB[0] = __builtin_amdgcn_mfma_f32_32x32x16_f16(B0.h8, bf1.h, accB[0], 0, 0, 0);
                accB[1] = __builtin_amdgcn_mfma_f32_32x32x16_f16(B1.h8, bf1.h, accB[1], 0, 0, 0);
            } else {
                accA[0] = __builtin_amdgcn_mfma_f32_32x32x16_f16(A0.h8, bf0.h, accA[0], 0, 0, 0);
                accA[1] = __builtin_amdgcn_mfma_f32_32x32x16_f16(A1.h8, bf0.h, accA[1], 0, 0, 0);
                accA[0] = __builtin_amdgcn_mfma_f32_32x32x16_f16(B0.h8, bf1.h, accA[0], 0, 0, 0);
                accA[1] = __builtin_amdgcn_mfma_f32_32x32x16_f16(B1.h8, bf1.h, accA[1], 0, 0, 0);
            }
            __builtin_amdgcn_s_setprio(0);
        }
        // chunk boundary: counted vmcnt (never 0 until the pipeline drains)
        if (c < 8) {
            if (c <= 5)      { asm volatile("s_waitcnt vmcnt(4)" ::: "memory"); }
            else if (c == 6) { asm volatile("s_waitcnt vmcnt(2)" ::: "memory"); }
            else             { asm volatile("s_waitcnt vmcnt(0)" ::: "memory"); }
            __builtin_amdgcn_sched_barrier(0);
            __builtin_amdgcn_s_barrier();
        }
    }

    // ---- store messages (sum the two chains) ----
    #pragma unroll
    for (int mt = 0; mt < 2; ++mt) {
        #pragma unroll
        for (int r = 0; r < 16; ++r) {
            int row = (r & 3) + 8 * (r >> 2) + 4 * h;
            int e = tileBase + mt * 32 + row;
            if (e < E) out[(size_t)e * 32 + l31] = accA[mt][r] + accB[mt][r];
        }
    }
}

extern "C" void kernel_launch(void* const* d_in, const int* in_sizes, int n_in,
                              void* d_out, int out_size, void* d_ws, size_t ws_size,
                              hipStream_t stream)
{
    // inputs: 0=h_v (unused), 1=h_w, 2=edge_features, 3=W1, 4=b1, 5=W2, 6=b2
    const float* h_w = (const float*)d_in[1];
    const float* ef  = (const float*)d_in[2];
    const float* W1  = (const float*)d_in[3];
    const float* b1  = (const float*)d_in[4];
    const float* W2  = (const float*)d_in[5];
    const float* b2  = (const float*)d_in[6];
    float* out = (float*)d_out;
    const int E = in_sizes[1] / 32;
    u16* ws = (u16*)d_ws;   // needs 143,616 B

    prep_kernel<<<35, 256, 0, stream>>>(W1, b1, W2, b2, ws);

    const int blocks = (E + 255) / 256;
    edge_kernel<<<blocks, 256, 0, stream>>>(h_w, ef, ws, out, E);
}

// Round 12
// 50.160 us; speedup vs baseline: 1.1465x; 1.0349x over previous
//
#include <hip/hip_runtime.h>

typedef unsigned short u16;
typedef _Float16 f16x2 __attribute__((ext_vector_type(2)));
typedef _Float16 f16x8 __attribute__((ext_vector_type(8)));
typedef float    f32x4  __attribute__((ext_vector_type(4)));
typedef float    f32x16 __attribute__((ext_vector_type(16)));

// Fragment k-map convention (same in BOTH operand slots — proven r1-r11):
//   k_local(lane, j) = (lane>>5)*4 + (j&3) + 8*(j>>2),  j = 0..7
// D layout (m74/m101): col = lane&31 (N), row = (r&3)+8*(r>>2)+4*(lane>>5) (M)

union U4 { uint4 u; f16x8 h; u16 s[8]; };
union HU { f16x2 h2[4]; f16x8 h8; };

// ---------------------------------------------------------------------------
// Prep (r8-identical): Bf = W2flat (2080 x 32, f16) in MFMA B-fragment order
// [0,133120); W1f fragments [133120,135168); b1p permuted bias f32
// [135168,135424): b1p[h][nt][r] = b1[nt*32 + (r&3)+8*(r>>2)+4h]
// ---------------------------------------------------------------------------
__global__ void prep_kernel(const float* __restrict__ W1,
                            const float* __restrict__ b1,
                            const float* __restrict__ W2,
                            const float* __restrict__ b2,
                            u16* __restrict__ ws)
{
    int id = blockIdx.x * 256 + threadIdx.x;
    if (id < 8320) {                       // 130 ksteps * 64 lanes
        int k2 = id >> 6, l = id & 63;
        int h = l >> 5, col = l & 31;
        U4 o;
        #pragma unroll
        for (int g = 0; g < 2; ++g) {
            int base4 = k2 * 16 + g * 8 + h * 4;   // 4-aligned, no 32-straddle
            f32x4 v;
            if (base4 < 2048) {
                int k1 = base4 >> 5, j32 = base4 & 31;
                v = *(const f32x4*)&W2[k1 * 1024 + col * 32 + j32];
            } else {
                v = *(const f32x4*)&b2[col * 32 + (base4 - 2048)];
            }
            #pragma unroll
            for (int j = 0; j < 4; ++j)
                o.h[g * 4 + j] = (_Float16)v[j];
        }
        *(uint4*)(ws + id * 8) = o.u;
    } else if (id < 8448) {                // W1 fragments: 2 ntiles * 64 lanes
        int idx = id - 8320;
        int nt = idx >> 6, l = idx & 63;
        int h = l >> 5, col = nt * 32 + (l & 31);
        U4 o;
        #pragma unroll
        for (int g = 0; g < 2; ++g)
            #pragma unroll
            for (int j = 0; j < 4; ++j) {
                int k = g * 8 + h * 4 + j;
                o.h[g * 4 + j] = (_Float16)W1[k * 64 + col];
            }
        *(uint4*)(ws + id * 8) = o.u;
    } else if (id < 8512) {                // b1p: 2h * 2nt * 16r floats
        int idx = id - 8448;
        int hh = idx >> 5, nt = (idx >> 4) & 1, r = idx & 15;
        int row = (r & 3) + 8 * (r >> 2) + 4 * hh;
        ((float*)(ws + 67584))[idx] = b1[nt * 32 + row];
    }
}

__device__ __forceinline__ void stage16(const void* g, void* l) {
    __builtin_amdgcn_global_load_lds(
        (const __attribute__((address_space(1))) void*)g,
        (__attribute__((address_space(3))) void*)l, 16, 0, 0);
}

// ---------------------------------------------------------------------------
// Main kernel: per-wave code = r8 VERBATIM (64 edges/wave, Q-in-regs
// transposed layer-1, 4 acc chains, 84 VGPR, 32 KB LDS B-dbuf, 2-phase
// __syncthreads). ONE change: 8 waves/block (512 threads). Rationale:
// r1-r11 all ran grid-limited at ~7 waves/CU (977 blocks / 256 CU = 3.8
// blocks/CU) — never resource-limited. 489 x 512-thread blocks -> 1.9
// blocks/CU, caps allow 2 (VGPR 84 -> 4 waves/SIMD; LDS 64 KB) -> ~16
// waves/CU resident (2.3x). B-staging also amortizes over 8 waves.
// ---------------------------------------------------------------------------
__global__ __launch_bounds__(512, 2) void edge_kernel(
    const float* __restrict__ h_w,
    const float* __restrict__ ef,
    const u16*  __restrict__ ws,
    float* __restrict__ out,
    int E)
{
    __shared__ alignas(16) u16 shm[16384];   // 32 KB = 2 x 16 KB chunks
    const int tid  = threadIdx.x;
    const int lane = tid & 63;
    const int l31  = lane & 31;
    const int h    = lane >> 5;
    const int tileBase = (blockIdx.x * 8 + (tid >> 6)) * 64;
    const char* wsb = (const char*)ws;
    char*       shb = (char*)shm;

    // ---- stage chunk 0 (16 KB = k1 0..7): 512 thr x 16 B x 2 rounds ----
    #pragma unroll
    for (int j = 0; j < 2; ++j)
        stage16(wsb + j * 8192 + tid * 16, shb + j * 8192 + tid * 16);

    // ---- h_w fragments (issued early; f16, kept in regs) ----
    f16x2 hwA[2][2][4];
    #pragma unroll
    for (int mt = 0; mt < 2; ++mt) {
        int e = tileBase + mt * 32 + l31;
        bool ok = e < E;
        f32x4 q0 = {}, q1 = {}, q2 = {}, q3 = {};
        if (ok) {
            const float* hp = h_w + (size_t)e * 32 + h * 4;
            q0 = *(const f32x4*)(hp);
            q1 = *(const f32x4*)(hp + 8);
            q2 = *(const f32x4*)(hp + 16);
            q3 = *(const f32x4*)(hp + 24);
        }
        hwA[mt][0][0] = f16x2{ (_Float16)q0[0], (_Float16)q0[1] };
        hwA[mt][0][1] = f16x2{ (_Float16)q0[2], (_Float16)q0[3] };
        hwA[mt][0][2] = f16x2{ (_Float16)q1[0], (_Float16)q1[1] };
        hwA[mt][0][3] = f16x2{ (_Float16)q1[2], (_Float16)q1[3] };
        hwA[mt][1][0] = f16x2{ (_Float16)q2[0], (_Float16)q2[1] };
        hwA[mt][1][1] = f16x2{ (_Float16)q2[2], (_Float16)q2[3] };
        hwA[mt][1][2] = f16x2{ (_Float16)q3[0], (_Float16)q3[1] };
        hwA[mt][1][3] = f16x2{ (_Float16)q3[2], (_Float16)q3[3] };
    }

    // ---- layer 1 (transposed): c = mfma(W1f as A, ef as B) ----
    const uint4* W1f = (const uint4*)(ws + 8320 * 8);
    U4 w1f0, w1f1;
    w1f0.u = W1f[lane];
    w1f1.u = W1f[64 + lane];
    const float* b1pf = (const float*)(ws + 67584);
    f32x4 bv[2][4];
    #pragma unroll
    for (int nt = 0; nt < 2; ++nt)
        #pragma unroll
        for (int qr = 0; qr < 4; ++qr)
            bv[nt][qr] = *(const f32x4*)(b1pf + h * 32 + nt * 16 + qr * 4);

    f16x2 Q[2][2][8][2];   // [mt][nt][p][hq]  — all indices compile-time
    #pragma unroll
    for (int mt = 0; mt < 2; ++mt) {
        int e = tileBase + mt * 32 + l31;
        bool ok = e < E;
        f32x4 g0 = {}, g1 = {};
        if (ok) {
            g0 = *(const f32x4*)&ef[e * 16 + h * 4];
            g1 = *(const f32x4*)&ef[e * 16 + 8 + h * 4];
        }
        U4 a;
        #pragma unroll
        for (int j = 0; j < 4; ++j) {
            a.h[j]     = (_Float16)g0[j];
            a.h[4 + j] = (_Float16)g1[j];
        }
        f32x16 c0 = {}, c1 = {};
        c0 = __builtin_amdgcn_mfma_f32_32x32x16_f16(w1f0.h, a.h, c0, 0, 0, 0);
        c1 = __builtin_amdgcn_mfma_f32_32x32x16_f16(w1f1.h, a.h, c1, 0, 0, 0);
        #pragma unroll
        for (int nt = 0; nt < 2; ++nt) {
            #pragma unroll
            for (int p = 0; p < 8; ++p) {
                float r0 = (nt ? c1[2 * p]     : c0[2 * p]);
                float r1 = (nt ? c1[2 * p + 1] : c0[2 * p + 1]);
                float v0 = fmaxf(r0 + bv[nt][p >> 1][(2 * p) & 3],     0.f);
                float v1 = fmaxf(r1 + bv[nt][p >> 1][(2 * p + 1) & 3], 0.f);
                f16x2 own = { (_Float16)v0, (_Float16)v1 };
                unsigned swu = __shfl_xor(__builtin_bit_cast(unsigned, own), 32, 64);
                f16x2 sw = __builtin_bit_cast(f16x2, swu);
                Q[mt][nt][p][0] = h ? sw : own;   // hq = 0 version
                Q[mt][nt][p][1] = h ? own : sw;   // hq = 1 version
            }
        }
    }

    // 4 independent accumulator chains: [mt][parity of k1]
    f32x16 accA[2] = {}, accB[2] = {};
    __syncthreads();   // chunk-0 stage drained

    // ---- K loop: 8 chunks x 8 k1, fully unrolled (static Q indexing) ----
    #pragma unroll
    for (int c = 0; c < 8; ++c) {
        if (c < 7) {                       // stage chunk c+1 (16 KB)
            #pragma unroll
            for (int j = 0; j < 2; ++j)
                stage16(wsb + (c + 1) * 16384 + j * 8192 + tid * 16,
                        shb + ((c + 1) & 1) * 16384 + j * 8192 + tid * 16);
        } else {                           // stage tail (2 KB, ksteps 128-129) into buf0
            if (tid < 128)
                stage16(wsb + 131072 + tid * 16, shb + tid * 16);
        }
        const char* bB = shb + (c & 1) * 16384;
        #pragma unroll
        for (int qq = 0; qq < 8; ++qq) {
            const int k1   = c * 8 + qq;
            const int nt   = k1 >> 5;
            const int q    = k1 & 31;
            const int pa   = ((q & 3) >> 1) + 2 * (q >> 3);
            const int half = q & 1;
            const int hq   = (q >> 2) & 1;
            U4 bf0, bf1;
            bf0.u = *(const uint4*)(bB + (2 * qq) * 1024 + lane * 16);
            bf1.u = *(const uint4*)(bB + (2 * qq + 1) * 1024 + lane * 16);
            _Float16 x0 = Q[0][nt][pa][hq][half];
            _Float16 x1 = Q[1][nt][pa][hq][half];
            f16x2 hh0 = { x0, x0 }, hh1 = { x1, x1 };
            HU A0, A1;
            #pragma unroll
            for (int rr = 0; rr < 4; ++rr) { A0.h2[rr] = hh0 * hwA[0][0][rr]; A1.h2[rr] = hh1 * hwA[1][0][rr]; }
            if (qq & 1) {
                accB[0] = __builtin_amdgcn_mfma_f32_32x32x16_f16(A0.h8, bf0.h, accB[0], 0, 0, 0);
                accB[1] = __builtin_amdgcn_mfma_f32_32x32x16_f16(A1.h8, bf0.h, accB[1], 0, 0, 0);
            } else {
                accA[0] = __builtin_amdgcn_mfma_f32_32x32x16_f16(A0.h8, bf0.h, accA[0], 0, 0, 0);
                accA[1] = __builtin_amdgcn_mfma_f32_32x32x16_f16(A1.h8, bf0.h, accA[1], 0, 0, 0);
            }
            #pragma unroll
            for (int rr = 0; rr < 4; ++rr) { A0.h2[rr] = hh0 * hwA[0][1][rr]; A1.h2[rr] = hh1 * hwA[1][1][rr]; }
            if (qq & 1) {
                accB[0] = __builtin_amdgcn_mfma_f32_32x32x16_f16(A0.h8, bf1.h, accB[0], 0, 0, 0);
                accB[1] = __builtin_amdgcn_mfma_f32_32x32x16_f16(A1.h8, bf1.h, accB[1], 0, 0, 0);
            } else {
                accA[0] = __builtin_amdgcn_mfma_f32_32x32x16_f16(A0.h8, bf1.h, accA[0], 0, 0, 0);
                accA[1] = __builtin_amdgcn_mfma_f32_32x32x16_f16(A1.h8, bf1.h, accA[1], 0, 0, 0);
            }
        }
        __syncthreads();
    }

    // ---- tail k1 = 64 (hdn == 1): A-frag = hwA directly, B in buf0 ----
    {
        U4 bf0, bf1;
        bf0.u = *(const uint4*)(shb + lane * 16);
        bf1.u = *(const uint4*)(shb + 1024 + lane * 16);
        HU A0, A1;
        #pragma unroll
        for (int rr = 0; rr < 4; ++rr) { A0.h2[rr] = hwA[0][0][rr]; A1.h2[rr] = hwA[1][0][rr]; }
        accA[0] = __builtin_amdgcn_mfma_f32_32x32x16_f16(A0.h8, bf0.h, accA[0], 0, 0, 0);
        accA[1] = __builtin_amdgcn_mfma_f32_32x32x16_f16(A1.h8, bf0.h, accA[1], 0, 0, 0);
        #pragma unroll
        for (int rr = 0; rr < 4; ++rr) { A0.h2[rr] = hwA[0][1][rr]; A1.h2[rr] = hwA[1][1][rr]; }
        accA[0] = __builtin_amdgcn_mfma_f32_32x32x16_f16(A0.h8, bf1.h, accA[0], 0, 0, 0);
        accA[1] = __builtin_amdgcn_mfma_f32_32x32x16_f16(A1.h8, bf1.h, accA[1], 0, 0, 0);
    }

    // ---- store messages (sum the two chains) ----
    #pragma unroll
    for (int mt = 0; mt < 2; ++mt) {
        #pragma unroll
        for (int r = 0; r < 16; ++r) {
            int row = (r & 3) + 8 * (r >> 2) + 4 * h;
            int e = tileBase + mt * 32 + row;
            if (e < E) out[(size_t)e * 32 + l31] = accA[mt][r] + accB[mt][r];
        }
    }
}

extern "C" void kernel_launch(void* const* d_in, const int* in_sizes, int n_in,
                              void* d_out, int out_size, void* d_ws, size_t ws_size,
                              hipStream_t stream)
{
    // inputs: 0=h_v (unused), 1=h_w, 2=edge_features, 3=W1, 4=b1, 5=W2, 6=b2
    const float* h_w = (const float*)d_in[1];
    const float* ef  = (const float*)d_in[2];
    const float* W1  = (const float*)d_in[3];
    const float* b1  = (const float*)d_in[4];
    const float* W2  = (const float*)d_in[5];
    const float* b2  = (const float*)d_in[6];
    float* out = (float*)d_out;
    const int E = in_sizes[1] / 32;
    u16* ws = (u16*)d_ws;   // needs 135,424 B

    prep_kernel<<<34, 256, 0, stream>>>(W1, b1, W2, b2, ws);

    const int blocks = (E + 511) / 512;   // 489 blocks of 8 waves
    edge_kernel<<<blocks, 512, 0, stream>>>(h_w, ef, ws, out, E);
}

// Round 13
// 50.061 us; speedup vs baseline: 1.1488x; 1.0020x over previous
//
#include <hip/hip_runtime.h>

typedef unsigned short u16;
typedef _Float16 f16x2 __attribute__((ext_vector_type(2)));
typedef _Float16 f16x8 __attribute__((ext_vector_type(8)));
typedef float    f32x4  __attribute__((ext_vector_type(4)));
typedef float    f32x16 __attribute__((ext_vector_type(16)));

// Fragment k-map convention (same in BOTH operand slots — proven r1-r12):
//   k_local(lane, j) = (lane>>5)*4 + (j&3) + 8*(j>>2),  j = 0..7
// D layout (m74/m101): col = lane&31 (N), row = (r&3)+8*(r>>2)+4*(lane>>5) (M)

union U4 { uint4 u; f16x8 h; u16 s[8]; };
union HU { f16x2 h2[4]; f16x8 h8; };

// ---------------------------------------------------------------------------
// Prep (r8-identical): Bf = W2flat (2080 x 32, f16) in MFMA B-fragment order
// [0,133120); W1f fragments [133120,135168); b1p permuted bias f32
// [135168,135424): b1p[h][nt][r] = b1[nt*32 + (r&3)+8*(r>>2)+4h]
// ---------------------------------------------------------------------------
__global__ void prep_kernel(const float* __restrict__ W1,
                            const float* __restrict__ b1,
                            const float* __restrict__ W2,
                            const float* __restrict__ b2,
                            u16* __restrict__ ws)
{
    int id = blockIdx.x * 256 + threadIdx.x;
    if (id < 8320) {                       // 130 ksteps * 64 lanes
        int k2 = id >> 6, l = id & 63;
        int h = l >> 5, col = l & 31;
        U4 o;
        #pragma unroll
        for (int g = 0; g < 2; ++g) {
            int base4 = k2 * 16 + g * 8 + h * 4;   // 4-aligned, no 32-straddle
            f32x4 v;
            if (base4 < 2048) {
                int k1 = base4 >> 5, j32 = base4 & 31;
                v = *(const f32x4*)&W2[k1 * 1024 + col * 32 + j32];
            } else {
                v = *(const f32x4*)&b2[col * 32 + (base4 - 2048)];
            }
            #pragma unroll
            for (int j = 0; j < 4; ++j)
                o.h[g * 4 + j] = (_Float16)v[j];
        }
        *(uint4*)(ws + id * 8) = o.u;
    } else if (id < 8448) {                // W1 fragments: 2 ntiles * 64 lanes
        int idx = id - 8320;
        int nt = idx >> 6, l = idx & 63;
        int h = l >> 5, col = nt * 32 + (l & 31);
        U4 o;
        #pragma unroll
        for (int g = 0; g < 2; ++g)
            #pragma unroll
            for (int j = 0; j < 4; ++j) {
                int k = g * 8 + h * 4 + j;
                o.h[g * 4 + j] = (_Float16)W1[k * 64 + col];
            }
        *(uint4*)(ws + id * 8) = o.u;
    } else if (id < 8512) {                // b1p: 2h * 2nt * 16r floats
        int idx = id - 8448;
        int hh = idx >> 5, nt = (idx >> 4) & 1, r = idx & 15;
        int row = (r & 3) + 8 * (r >> 2) + 4 * hh;
        ((float*)(ws + 67584))[idx] = b1[nt * 32 + row];
    }
}

__device__ __forceinline__ void stage16(const void* g, void* l) {
    __builtin_amdgcn_global_load_lds(
        (const __attribute__((address_space(1))) void*)g,
        (__attribute__((address_space(3))) void*)l, 16, 0, 0);
}

// ---------------------------------------------------------------------------
// Main kernel: r8 structure EXACTLY (256 thr, 4 waves, 64 edges/wave, 32 KB
// LDS B-dbuf, Q-in-regs transposed layer-1, 4 acc chains, 8 chunk barriers)
// + ONE change: distance-4 rotating REGISTER prefetch of the B-fragment
// pairs (pf[4][2], static indices). Rationale: per-body ds_read->MFMA
// dependency (~100+ cyc lgkm stall, uncoverable at ~1.6 in-phase waves/SIMD)
// is the last untested mechanism — r5's rotation ran inside a spill, r10's
// never compiled. Now each ds_read has ~4 bodies (~300 cyc) issue-to-use.
// ---------------------------------------------------------------------------
__global__ __launch_bounds__(256, 3) void edge_kernel(
    const float* __restrict__ h_w,
    const float* __restrict__ ef,
    const u16*  __restrict__ ws,
    float* __restrict__ out,
    int E)
{
    __shared__ alignas(16) u16 shm[16384];   // 32 KB
    const int tid  = threadIdx.x;
    const int lane = tid & 63;
    const int l31  = lane & 31;
    const int h    = lane >> 5;
    const int tileBase = (blockIdx.x * 4 + (tid >> 6)) * 64;
    const char* wsb = (const char*)ws;
    char*       shb = (char*)shm;

    // ---- stage chunk 0 (16 KB = k1 0..7) ----
    #pragma unroll
    for (int j = 0; j < 4; ++j)
        stage16(wsb + j * 4096 + tid * 16, shb + j * 4096 + tid * 16);

    // ---- h_w fragments (issued early; f16, kept in regs) ----
    f16x2 hwA[2][2][4];
    #pragma unroll
    for (int mt = 0; mt < 2; ++mt) {
        int e = tileBase + mt * 32 + l31;
        bool ok = e < E;
        f32x4 q0 = {}, q1 = {}, q2 = {}, q3 = {};
        if (ok) {
            const float* hp = h_w + (size_t)e * 32 + h * 4;
            q0 = *(const f32x4*)(hp);
            q1 = *(const f32x4*)(hp + 8);
            q2 = *(const f32x4*)(hp + 16);
            q3 = *(const f32x4*)(hp + 24);
        }
        hwA[mt][0][0] = f16x2{ (_Float16)q0[0], (_Float16)q0[1] };
        hwA[mt][0][1] = f16x2{ (_Float16)q0[2], (_Float16)q0[3] };
        hwA[mt][0][2] = f16x2{ (_Float16)q1[0], (_Float16)q1[1] };
        hwA[mt][0][3] = f16x2{ (_Float16)q1[2], (_Float16)q1[3] };
        hwA[mt][1][0] = f16x2{ (_Float16)q2[0], (_Float16)q2[1] };
        hwA[mt][1][1] = f16x2{ (_Float16)q2[2], (_Float16)q2[3] };
        hwA[mt][1][2] = f16x2{ (_Float16)q3[0], (_Float16)q3[1] };
        hwA[mt][1][3] = f16x2{ (_Float16)q3[2], (_Float16)q3[3] };
    }

    // ---- layer 1 (transposed): c = mfma(W1f as A, ef as B) ----
    const uint4* W1f = (const uint4*)(ws + 8320 * 8);
    U4 w1f0, w1f1;
    w1f0.u = W1f[lane];
    w1f1.u = W1f[64 + lane];
    const float* b1pf = (const float*)(ws + 67584);
    f32x4 bv[2][4];
    #pragma unroll
    for (int nt = 0; nt < 2; ++nt)
        #pragma unroll
        for (int qr = 0; qr < 4; ++qr)
            bv[nt][qr] = *(const f32x4*)(b1pf + h * 32 + nt * 16 + qr * 4);

    f16x2 Q[2][2][8][2];   // [mt][nt][p][hq]  — all indices compile-time
    #pragma unroll
    for (int mt = 0; mt < 2; ++mt) {
        int e = tileBase + mt * 32 + l31;
        bool ok = e < E;
        f32x4 g0 = {}, g1 = {};
        if (ok) {
            g0 = *(const f32x4*)&ef[e * 16 + h * 4];
            g1 = *(const f32x4*)&ef[e * 16 + 8 + h * 4];
        }
        U4 a;
        #pragma unroll
        for (int j = 0; j < 4; ++j) {
            a.h[j]     = (_Float16)g0[j];
            a.h[4 + j] = (_Float16)g1[j];
        }
        f32x16 c0 = {}, c1 = {};
        c0 = __builtin_amdgcn_mfma_f32_32x32x16_f16(w1f0.h, a.h, c0, 0, 0, 0);
        c1 = __builtin_amdgcn_mfma_f32_32x32x16_f16(w1f1.h, a.h, c1, 0, 0, 0);
        #pragma unroll
        for (int nt = 0; nt < 2; ++nt) {
            #pragma unroll
            for (int p = 0; p < 8; ++p) {
                float r0 = (nt ? c1[2 * p]     : c0[2 * p]);
                float r1 = (nt ? c1[2 * p + 1] : c0[2 * p + 1]);
                float v0 = fmaxf(r0 + bv[nt][p >> 1][(2 * p) & 3],     0.f);
                float v1 = fmaxf(r1 + bv[nt][p >> 1][(2 * p + 1) & 3], 0.f);
                f16x2 own = { (_Float16)v0, (_Float16)v1 };
                unsigned swu = __shfl_xor(__builtin_bit_cast(unsigned, own), 32, 64);
                f16x2 sw = __builtin_bit_cast(f16x2, swu);
                Q[mt][nt][p][0] = h ? sw : own;   // hq = 0 version
                Q[mt][nt][p][1] = h ? own : sw;   // hq = 1 version
            }
        }
    }

    // 4 independent accumulator chains: [mt][parity of k1]
    f32x16 accA[2] = {}, accB[2] = {};
    __syncthreads();   // chunk-0 stage drained

    // ---- K loop: 8 chunks x 8 k1; distance-4 reg prefetch of B pairs ----
    #pragma unroll
    for (int c = 0; c < 8; ++c) {
        if (c < 7) {                       // stage chunk c+1 (16 KB)
            #pragma unroll
            for (int j = 0; j < 4; ++j)
                stage16(wsb + (c + 1) * 16384 + j * 4096 + tid * 16,
                        shb + ((c + 1) & 1) * 16384 + j * 4096 + tid * 16);
        } else {                           // stage tail (2 KB, ksteps 128-129) into buf0
            if (tid < 128)
                stage16(wsb + 131072 + tid * 16, shb + tid * 16);
        }
        const char* bB = shb + (c & 1) * 16384;
        U4 pf[4][2];                       // distance-4 rotating prefetch
        #pragma unroll
        for (int p = 0; p < 4; ++p) {
            pf[p][0].u = *(const uint4*)(bB + (2 * p) * 1024 + lane * 16);
            pf[p][1].u = *(const uint4*)(bB + (2 * p + 1) * 1024 + lane * 16);
        }
        #pragma unroll
        for (int qq = 0; qq < 8; ++qq) {
            U4 bf0 = pf[qq & 3][0], bf1 = pf[qq & 3][1];
            if (qq + 4 < 8) {              // refill slot with k1+4 (static idx)
                pf[qq & 3][0].u = *(const uint4*)(bB + (2 * (qq + 4)) * 1024 + lane * 16);
                pf[qq & 3][1].u = *(const uint4*)(bB + (2 * (qq + 4) + 1) * 1024 + lane * 16);
            }
            const int k1   = c * 8 + qq;
            const int nt   = k1 >> 5;
            const int q    = k1 & 31;
            const int pa   = ((q & 3) >> 1) + 2 * (q >> 3);
            const int half = q & 1;
            const int hq   = (q >> 2) & 1;
            _Float16 x0 = Q[0][nt][pa][hq][half];
            _Float16 x1 = Q[1][nt][pa][hq][half];
            f16x2 hh0 = { x0, x0 }, hh1 = { x1, x1 };
            HU A0, A1;
            #pragma unroll
            for (int rr = 0; rr < 4; ++rr) { A0.h2[rr] = hh0 * hwA[0][0][rr]; A1.h2[rr] = hh1 * hwA[1][0][rr]; }
            if (qq & 1) {
                accB[0] = __builtin_amdgcn_mfma_f32_32x32x16_f16(A0.h8, bf0.h, accB[0], 0, 0, 0);
                accB[1] = __builtin_amdgcn_mfma_f32_32x32x16_f16(A1.h8, bf0.h, accB[1], 0, 0, 0);
            } else {
                accA[0] = __builtin_amdgcn_mfma_f32_32x32x16_f16(A0.h8, bf0.h, accA[0], 0, 0, 0);
                accA[1] = __builtin_amdgcn_mfma_f32_32x32x16_f16(A1.h8, bf0.h, accA[1], 0, 0, 0);
            }
            #pragma unroll
            for (int rr = 0; rr < 4; ++rr) { A0.h2[rr] = hh0 * hwA[0][1][rr]; A1.h2[rr] = hh1 * hwA[1][1][rr]; }
            if (qq & 1) {
                accB[0] = __builtin_amdgcn_mfma_f32_32x32x16_f16(A0.h8, bf1.h, accB[0], 0, 0, 0);
                accB[1] = __builtin_amdgcn_mfma_f32_32x32x16_f16(A1.h8, bf1.h, accB[1], 0, 0, 0);
            } else {
                accA[0] = __builtin_amdgcn_mfma_f32_32x32x16_f16(A0.h8, bf1.h, accA[0], 0, 0, 0);
                accA[1] = __builtin_amdgcn_mfma_f32_32x32x16_f16(A1.h8, bf1.h, accA[1], 0, 0, 0);
            }
        }
        __syncthreads();
    }

    // ---- tail k1 = 64 (hdn == 1): A-frag = hwA directly, B in buf0 ----
    {
        U4 bf0, bf1;
        bf0.u = *(const uint4*)(shb + lane * 16);
        bf1.u = *(const uint4*)(shb + 1024 + lane * 16);
        HU A0, A1;
        #pragma unroll
        for (int rr = 0; rr < 4; ++rr) { A0.h2[rr] = hwA[0][0][rr]; A1.h2[rr] = hwA[1][0][rr]; }
        accA[0] = __builtin_amdgcn_mfma_f32_32x32x16_f16(A0.h8, bf0.h, accA[0], 0, 0, 0);
        accA[1] = __builtin_amdgcn_mfma_f32_32x32x16_f16(A1.h8, bf0.h, accA[1], 0, 0, 0);
        #pragma unroll
        for (int rr = 0; rr < 4; ++rr) { A0.h2[rr] = hwA[0][1][rr]; A1.h2[rr] = hwA[1][1][rr]; }
        accA[0] = __builtin_amdgcn_mfma_f32_32x32x16_f16(A0.h8, bf1.h, accA[0], 0, 0, 0);
        accA[1] = __builtin_amdgcn_mfma_f32_32x32x16_f16(A1.h8, bf1.h, accA[1], 0, 0, 0);
    }

    // ---- store messages (sum the two chains) ----
    #pragma unroll
    for (int mt = 0; mt < 2; ++mt) {
        #pragma unroll
        for (int r = 0; r < 16; ++r) {
            int row = (r & 3) + 8 * (r >> 2) + 4 * h;
            int e = tileBase + mt * 32 + row;
            if (e < E) out[(size_t)e * 32 + l31] = accA[mt][r] + accB[mt][r];
        }
    }
}

extern "C" void kernel_launch(void* const* d_in, const int* in_sizes, int n_in,
                              void* d_out, int out_size, void* d_ws, size_t ws_size,
                              hipStream_t stream)
{
    // inputs: 0=h_v (unused), 1=h_w, 2=edge_features, 3=W1, 4=b1, 5=W2, 6=b2
    const float* h_w = (const float*)d_in[1];
    const float* ef  = (const float*)d_in[2];
    const float* W1  = (const float*)d_in[3];
    const float* b1  = (const float*)d_in[4];
    const float* W2  = (const float*)d_in[5];
    const float* b2  = (const float*)d_in[6];
    float* out = (float*)d_out;
    const int E = in_sizes[1] / 32;
    u16* ws = (u16*)d_ws;   // needs 135,424 B

    prep_kernel<<<34, 256, 0, stream>>>(W1, b1, W2, b2, ws);

    const int blocks = (E + 255) / 256;
    edge_kernel<<<blocks, 256, 0, stream>>>(h_w, ef, ws, out, E);
}